// Round 18
// baseline (20831.842 us; speedup 1.0000x reference)
//
#include <hip/hip_runtime.h>

// k-means (Lloyd), N=500000 D=64 K=256 ITERS=10, fp32.
// Round 18: wave-owns-centroid-tile restructure. r17 (clean memory, SLOWER)
// + r12 (spilled, faster) proved the wall is the per-wave serial chain, not
// spill. Now each wave holds its 16-cent tile's A-frags in REGISTERS (16
// VGPR, loaded once; no cent LDS at all); 128-point batches are staged in
// LDS (bf16 hi/lo frags + fp32 copy); per group a wave does only 4 ds_read +
// 6 MFMA + 4-score -> all 16 waves cooperate on every group (serial chain
// 16x shorter, parallelized across waves). Per-tile (min,idx,mask) partials
// -> 128-thread reduce (ascending scan = first-index tie-break) -> proven
// exact-fp32 refine on near-ties -> owner-lane LDS accumulation from the
// fp32 copy. Live regs ~55: fits the 1024-thread 64-VGPR cap.

#define D 64
#define K 256
#define ITERS 10
#define BLOCK 1024
#define NBLK 256
#define EPS 2e-3f
#define SPAD 66
#define BATCH 128
#define NG 8                       // groups of 16 points per batch
#define PART_STRIDE (K * D + K)    // 16640 floats per block partial
// LDS: fh 16K + fl 16K + xs 32K + pmin 8K + pmeta 8K + sxsq .5K + sbk .5K
//      + sums 67.5K(SPAD) + cnt 1K = 151552 B (148 KB)
#define SMEM_BYTES (16384 + 16384 + 32768 + 8192 + 8192 + 512 + 512 + 256 * SPAD * 4 + 1024)

typedef __attribute__((ext_vector_type(8))) short bf16x8;
typedef __attribute__((ext_vector_type(4))) float f32x4;

__device__ __forceinline__ unsigned short f2bf(float f) {
    unsigned u = __builtin_bit_cast(unsigned, f);
    u = u + 0x7FFFu + ((u >> 16) & 1u);   // RNE
    return (unsigned short)(u >> 16);
}
__device__ __forceinline__ float bf2f(unsigned short h) {
    unsigned u = ((unsigned)h) << 16;
    return __builtin_bit_cast(float, u);
}

// ---------------------------------------------------------------------------
__global__ void init_gather(const float* __restrict__ x,
                            const int* __restrict__ idx,
                            float* __restrict__ cent,
                            float* __restrict__ csq) {
    int k = blockIdx.x;
    int d = threadIdx.x;
    float v = x[(size_t)idx[k] * D + d];
    cent[k * D + d] = v;
    float s = v * v;
    #pragma unroll
    for (int off = 32; off > 0; off >>= 1) s += __shfl_down(s, off);
    if (d == 0) csq[k] = s;
}

// ---------------------------------------------------------------------------
__global__ __launch_bounds__(BLOCK, 4) void lloyd_batch(
        const float* __restrict__ x,
        const float* __restrict__ cent,
        const float* __restrict__ csq_g,
        float* __restrict__ parts,
        int N, int ppb) {
    extern __shared__ char smem[];
    short* fh = (short*)smem;                        // [NG][2][4][16][8] hi
    short* fl = fh + 8192;                           // lo
    float* xs = (float*)(fl + 8192);                 // [128][64] fp32
    float* pmin = xs + 8192;                         // [16][128]
    unsigned* pmeta = (unsigned*)(pmin + 2048);      // [16][128] idx<<16|mask
    float* sxsq = (float*)(pmeta + 2048);            // [128]
    int* sbk = (int*)(sxsq + 128);                   // [128]
    float* s_sums = (float*)(sbk + 128);             // [256][SPAD]
    float* s_cnt = s_sums + 256 * SPAD;              // [256]

    const int tid = threadIdx.x;
    const int wv = tid >> 6;          // 0..15: owns cent tile wv
    const int lane = tid & 63;
    const int c15 = lane & 15;
    const int g4 = lane >> 4;

    // ---- persistent A-frags: this wave's 16 cents, -2c hi/lo ----
    bf16x8 ah[2], al[2];
    {
        const float* cw = cent + (size_t)(wv * 16 + c15) * D;
        #pragma unroll
        for (int s = 0; s < 2; ++s) {
            const float4* cp = (const float4*)(cw + (s * 4 + g4) * 8);
            float4 u0 = cp[0], u1 = cp[1];
            float cv[8] = {u0.x, u0.y, u0.z, u0.w, u1.x, u1.y, u1.z, u1.w};
            #pragma unroll
            for (int e = 0; e < 8; ++e) {
                float v = -2.0f * cv[e];
                unsigned short h = f2bf(v);
                ah[s][e] = (short)h;
                al[s][e] = (short)f2bf(v - bf2f(h));
            }
        }
    }
    f32x4 q = *(const f32x4*)(csq_g + wv * 16 + g4 * 4);   // csq of scored cents

    for (int i = tid; i < 256 * SPAD; i += BLOCK) s_sums[i] = 0.0f;
    if (tid < K) s_cnt[tid] = 0.0f;
    if (tid < BATCH) sxsq[tid] = 0.0f;
    __syncthreads();

    const int base = blockIdx.x * ppb;
    int lim = base + ppb;
    if (lim > N) lim = N;
    const int nbatch = (lim > base) ? ((lim - base + BATCH - 1) / BATCH) : 0;

    #pragma unroll 1
    for (int b = 0; b < nbatch; ++b) {
        const int pstart = base + b * BATCH;

        // ---- stage 128 points: bf16 hi/lo frags + fp32 copy + xsq ----
        {
            int p = tid >> 3;
            int db = tid & 7;                 // dim-chunk: s=db>>2, g4w=db&3
            int src = pstart + p;
            if (src >= lim) src = lim - 1;
            const float4* xp = (const float4*)(x + (size_t)src * D + db * 8);
            float4 u0 = xp[0], u1 = xp[1];
            float v[8] = {u0.x, u0.y, u0.z, u0.w, u1.x, u1.y, u1.z, u1.w};
            float ssq = 0.0f;
            bf16x8 h8, l8;
            #pragma unroll
            for (int e = 0; e < 8; ++e) {
                ssq += v[e] * v[e];
                unsigned short h = f2bf(v[e]);
                h8[e] = (short)h;
                l8[e] = (short)f2bf(v[e] - bf2f(h));
            }
            atomicAdd(&sxsq[p], ssq);
            int fi = ((((p >> 4) * 2 + (db >> 2)) * 4 + (db & 3)) * 16 + (p & 15)) * 8;
            *(bf16x8*)&fh[fi] = h8;
            *(bf16x8*)&fl[fi] = l8;
            float* xd = xs + p * D + db * 8;
            *(float4*)xd = u0;
            *(float4*)(xd + 4) = u1;
        }
        __syncthreads();

        // ---- MFMA phase: wave wv scores its tile vs all NG groups ----
        #pragma unroll 1
        for (int g = 0; g < NG; ++g) {
            int bi0 = (((g * 2 + 0) * 4 + g4) * 16 + c15) * 8;
            int bi1 = (((g * 2 + 1) * 4 + g4) * 16 + c15) * 8;
            bf16x8 bh0 = *(const bf16x8*)&fh[bi0];
            bf16x8 bl0 = *(const bf16x8*)&fl[bi0];
            bf16x8 bh1 = *(const bf16x8*)&fh[bi1];
            bf16x8 bl1 = *(const bf16x8*)&fl[bi1];
            f32x4 acc = {0.f, 0.f, 0.f, 0.f};
            acc = __builtin_amdgcn_mfma_f32_16x16x32_bf16(ah[0], bh0, acc, 0, 0, 0);
            acc = __builtin_amdgcn_mfma_f32_16x16x32_bf16(ah[0], bl0, acc, 0, 0, 0);
            acc = __builtin_amdgcn_mfma_f32_16x16x32_bf16(al[0], bh0, acc, 0, 0, 0);
            acc = __builtin_amdgcn_mfma_f32_16x16x32_bf16(ah[1], bh1, acc, 0, 0, 0);
            acc = __builtin_amdgcn_mfma_f32_16x16x32_bf16(ah[1], bl1, acc, 0, 0, 0);
            acc = __builtin_amdgcn_mfma_f32_16x16x32_bf16(al[1], bh1, acc, 0, 0, 0);

            float lmin = 3.4e38f;
            int lidx = 0;
            unsigned lmask = 0;
            #pragma unroll
            for (int r = 0; r < 4; ++r) {
                float sc = acc[r] + q[r];
                int it = g4 * 4 + r;          // in-tile cent index
                if (sc < lmin) { lmin = sc; lidx = it; }
                if (sc <= lmin + EPS) lmask |= 1u << it;   // running-min superset
            }
            #pragma unroll
            for (int off = 16; off <= 32; off <<= 1) {
                float so = __shfl_xor(lmin, off);
                int io = __shfl_xor(lidx, off);
                unsigned mo = __shfl_xor(lmask, off);
                lmask |= mo;
                if (so < lmin || (so == lmin && io < lidx)) { lmin = so; lidx = io; }
            }
            if (g4 == 0) {
                pmin[wv * BATCH + g * 16 + c15] = lmin;
                pmeta[wv * BATCH + g * 16 + c15] = ((unsigned)lidx << 16) | lmask;
            }
        }
        __syncthreads();

        // ---- reduce (+ exact fp32 refine): threads 0..127, one point each ----
        if (tid < BATCH) {
            int p = tid;
            float gmin = 3.4e38f;
            int bk = 0;
            #pragma unroll 1
            for (int w = 0; w < 16; ++w) {        // ascending w = first-index ties
                float v = pmin[w * BATCH + p];
                if (v < gmin) {
                    gmin = v;
                    bk = w * 16 + (int)((pmeta[w * BATCH + p] >> 16) & 15u);
                }
            }
            int ncand = 0;
            #pragma unroll 1
            for (int w = 0; w < 16; ++w)
                if (pmin[w * BATCH + p] <= gmin + EPS)
                    ncand += __popc(pmeta[w * BATCH + p] & 0xFFFFu);
            if (ncand >= 2) {
                float xsq = sxsq[p];
                float eb = 3.4e38f;
                int em = 0x7fffffff;
                const float* xr = xs + p * D;
                #pragma unroll 1
                for (int w = 0; w < 16; ++w) {
                    if (pmin[w * BATCH + p] > gmin + EPS) continue;
                    unsigned mm = pmeta[w * BATCH + p] & 0xFFFFu;
                    while (mm) {
                        int bit = __ffs(mm) - 1;
                        mm &= mm - 1;
                        int m = w * 16 + bit;
                        const float* cr = cent + (size_t)m * D;
                        float dot = 0.0f;
                        #pragma unroll
                        for (int d4 = 0; d4 < D; d4 += 4) {
                            float4 c4 = *(const float4*)(cr + d4);
                            dot += c4.x * xr[d4 + 0];
                            dot += c4.y * xr[d4 + 1];
                            dot += c4.z * xr[d4 + 2];
                            dot += c4.w * xr[d4 + 3];
                        }
                        float es = xsq - 2.0f * dot + csq_g[m];
                        if (es < eb || (es == eb && m < em)) { eb = es; em = m; }
                    }
                }
                bk = em;
            }
            sbk[p] = bk;
        }
        __syncthreads();

        // ---- accumulate: wave wv handles points wv*8 .. +8, lane = dim ----
        #pragma unroll 1
        for (int j = 0; j < 8; ++j) {
            int p = wv * 8 + j;
            if (pstart + p < lim) {
                int bk = sbk[p];
                float vv = xs[p * D + lane];
                atomicAdd(&s_sums[bk * SPAD + lane], vv);
                if (lane == 0) atomicAdd(&s_cnt[bk], 1.0f);
            }
        }
        if (tid < BATCH) sxsq[tid] = 0.0f;   // reset for next batch
        __syncthreads();
    }

    // ---- flush block partials (unpad) ----
    float* part = parts + (size_t)blockIdx.x * PART_STRIDE;
    for (int i = tid; i < K * D; i += BLOCK) {
        int k = i >> 6, d = i & 63;
        part[i] = s_sums[k * SPAD + d];
    }
    if (tid < K) part[K * D + tid] = s_cnt[tid];
}

// ---------------------------------------------------------------------------
// fused reduce + finalize: one cent per block, 256 threads (4 slices x 64 dims)
__global__ void finalize2(float* __restrict__ cent,
                          const float* __restrict__ parts,
                          float* __restrict__ csq_g,
                          int nb) {
    __shared__ float tmp[4][64];
    __shared__ float tcnt[4];
    int k = blockIdx.x;
    int sl = threadIdx.x >> 6;
    int d = threadIdx.x & 63;
    float s = 0.0f, c = 0.0f;
    for (int b = sl; b < nb; b += 4) {
        const float* pb = parts + (size_t)b * PART_STRIDE;
        s += pb[k * D + d];
        c += pb[K * D + k];
    }
    tmp[sl][d] = s;
    if (d == 0) tcnt[sl] = c;
    __syncthreads();
    if (sl == 0) {
        float st = tmp[0][d] + tmp[1][d] + tmp[2][d] + tmp[3][d];
        float ct = tcnt[0] + tcnt[1] + tcnt[2] + tcnt[3];
        float oldc = cent[k * D + d];
        float nc = (ct > 0.0f) ? (st / ct) : oldc;
        cent[k * D + d] = nc;
        float v = nc * nc;
        #pragma unroll
        for (int off = 32; off > 0; off >>= 1) v += __shfl_down(v, off);
        if (d == 0) csq_g[k] = v;
    }
}

// ---------------------------------------------------------------------------
extern "C" void kernel_launch(void* const* d_in, const int* in_sizes, int n_in,
                              void* d_out, int out_size, void* d_ws, size_t ws_size,
                              hipStream_t stream) {
    const float* x = (const float*)d_in[0];
    const int* init_idx = (const int*)d_in[1];

    int N = in_sizes[0] / D;

    float* cent = (float*)d_out;

    // ws layout: parts[nb][PART_STRIDE] | csq[K]
    int nb = NBLK;
    size_t need = ((size_t)NBLK * PART_STRIDE + K) * sizeof(float);
    if (ws_size < need) {
        size_t avail = (ws_size > (size_t)K * sizeof(float))
                           ? ws_size - (size_t)K * sizeof(float) : 0;
        nb = (int)(avail / (PART_STRIDE * sizeof(float)));
        if (nb < 1) nb = 1;
    }
    float* parts = (float*)d_ws;
    float* csq = parts + (size_t)nb * PART_STRIDE;

    hipFuncSetAttribute(reinterpret_cast<const void*>(lloyd_batch),
                        hipFuncAttributeMaxDynamicSharedMemorySize, SMEM_BYTES);

    init_gather<<<dim3(K), dim3(64), 0, stream>>>(x, init_idx, cent, csq);

    int ppb = (N + nb - 1) / nb;
    for (int it = 0; it < ITERS; ++it) {
        lloyd_batch<<<dim3(nb), dim3(BLOCK), SMEM_BYTES, stream>>>(
            x, cent, csq, parts, N, ppb);
        finalize2<<<dim3(K), dim3(256), 0, stream>>>(cent, parts, csq, nb);
    }
}

// Round 19
// 2372.260 us; speedup vs baseline: 8.7814x; 8.7814x over previous
//
#include <hip/hip_runtime.h>

// k-means (Lloyd), N=500000 D=64 K=256 ITERS=10, fp32.
// Round 19: REVERT to round 15 (best verified: 2374us, absmax 0.024).
// r18's wave-owns-tile restructure regressed 9x (batch-reduce serialization:
// 128/1024 threads in dependent-LDS-read loops, 4 barriers/batch, 27.9M bank
// conflicts). The fused design below is the empirical optimum of 18 variants:
// ~232us/iter, insensitive to occupancy/spill/EPS/ILP within this toolchain's
// register-cap constraints (1024-thr blocks hard-cap 64 VGPR; every latency-
// pipelining attempt spilled). Numerics: hi/lo bf16 3-term MFMA scores +
// exact-fp32 refine on near-ties (EPS 2e-3), owner-lane LDS accumulation.

#define D 64
#define K 256
#define ITERS 10
#define BLOCK 1024
#define NB_MAX 256
#define EPS 2e-3f
#define SPAD 66
#define PART_STRIDE (K * D + K)   // 16640 floats per block partial
// LDS: chi 32KB + clo 32KB + csq 1KB + sums(padded) 66KB + cnt 1KB = 132KB
#define SMEM_BYTES (32768 * 2 + (256 + 256 * SPAD + 256) * 4)

typedef __attribute__((ext_vector_type(8))) short bf16x8;
typedef __attribute__((ext_vector_type(4))) float f32x4;
typedef __attribute__((ext_vector_type(4))) short short4v;

__device__ __forceinline__ unsigned short f2bf(float f) {
    unsigned u = __builtin_bit_cast(unsigned, f);
    u = u + 0x7FFFu + ((u >> 16) & 1u);   // RNE
    return (unsigned short)(u >> 16);
}
__device__ __forceinline__ float bf2f(unsigned short h) {
    unsigned u = ((unsigned)h) << 16;
    return __builtin_bit_cast(float, u);
}

// ---------------------------------------------------------------------------
__global__ void init_gather(const float* __restrict__ x,
                            const int* __restrict__ idx,
                            float* __restrict__ cent,
                            float* __restrict__ csq) {
    int k = blockIdx.x;
    int d = threadIdx.x;
    float v = x[(size_t)idx[k] * D + d];
    cent[k * D + d] = v;
    float s = v * v;
    #pragma unroll
    for (int off = 32; off > 0; off >>= 1) s += __shfl_down(s, off);
    if (d == 0) csq[k] = s;
}

// ---------------------------------------------------------------------------
// score -> argmin (+ exact fp32 refine on near-ties).
__device__ __forceinline__ int resolve_bk(
        const f32x4 (&acc)[16], const float* __restrict__ s_csq,
        const float* __restrict__ cent, const float* __restrict__ xr,
        int g4) {
    // pass 1: global approx min
    float gmin = 3.4e38f;
    int gidx = 0;
    #pragma unroll
    for (int t = 0; t < 16; ++t) {
        f32x4 q = *(const f32x4*)&s_csq[t * 16 + (g4 << 2)];
        #pragma unroll
        for (int r = 0; r < 4; ++r) {
            float sc = acc[t][r] + q[r];
            int m = t * 16 + (g4 << 2) + r;
            if (sc < gmin) { gmin = sc; gidx = m; }
        }
    }
    #pragma unroll
    for (int off = 16; off <= 32; off <<= 1) {
        float so = __shfl_xor(gmin, off);
        int io = __shfl_xor(gidx, off);
        if (so < gmin || (so == gmin && io < gidx)) { gmin = so; gidx = io; }
    }
    // pass 2: candidate mask vs FINAL min
    unsigned long long cmask = 0;
    #pragma unroll
    for (int t = 0; t < 16; ++t) {
        f32x4 q = *(const f32x4*)&s_csq[t * 16 + (g4 << 2)];
        #pragma unroll
        for (int r = 0; r < 4; ++r) {
            float sc = acc[t][r] + q[r];
            if (sc <= gmin + EPS) cmask |= 1ull << (t * 4 + r);
        }
    }
    int nb_ = __popcll(cmask);
    nb_ += __shfl_xor(nb_, 16);
    nb_ += __shfl_xor(nb_, 32);

    int bk = gidx;
    if (__any(nb_ >= 2)) {
        float xsq = 0.0f;
        #pragma unroll
        for (int d = 0; d < D; ++d) xsq += xr[d] * xr[d];
        float eb = 3.4e38f;
        int em = 0x7fffffff;
        unsigned long long mm = cmask;
        while (mm) {
            int b = __ffsll((unsigned long long)mm) - 1;
            mm &= mm - 1;
            int m = ((b >> 2) << 4) + (g4 << 2) + (b & 3);
            const float* cr = cent + m * D;
            float dot = 0.0f;
            #pragma unroll
            for (int d4 = 0; d4 < D; d4 += 4) {
                float4 c4 = *(const float4*)(cr + d4);
                dot += c4.x * xr[d4 + 0];
                dot += c4.y * xr[d4 + 1];
                dot += c4.z * xr[d4 + 2];
                dot += c4.w * xr[d4 + 3];
            }
            float es = xsq - 2.0f * dot + s_csq[m];
            if (es < eb || (es == eb && m < em)) { eb = es; em = m; }
        }
        #pragma unroll
        for (int off = 16; off <= 32; off <<= 1) {
            float so = __shfl_xor(eb, off);
            int io = __shfl_xor(em, off);
            if (so < eb || (so == eb && io < em)) { eb = so; em = io; }
        }
        bk = em;
    }
    return bk;
}

// ---------------------------------------------------------------------------
// fused assign (MFMA + exact refine) + owner-lane LDS accumulate.
// chi/clo LDS layout: [8 k-chunks][256 cents][8 elems] bf16 of (-2*c).
__global__ __launch_bounds__(BLOCK, 4) void assign_mfma(
        const float* __restrict__ x,
        const float* __restrict__ cent,
        const float* __restrict__ csq_g,
        float* __restrict__ parts,
        int N, int ppb) {
    extern __shared__ char smem[];
    short* chi = (short*)smem;                       // 16384 shorts
    short* clo = chi + 16384;                        // 16384 shorts
    float* s_csq = (float*)(clo + 16384);            // 256
    float* s_sums = s_csq + 256;                     // 256*SPAD
    float* s_cnt = s_sums + 256 * SPAD;              // 256

    const int tid = threadIdx.x;

    // ---- stage centroids as -2c hi/lo bf16; zero LDS partials ----
    for (int i = tid; i < (K * D) / 4; i += BLOCK) {
        float4 c4 = ((const float4*)cent)[i];
        int elem = i * 4;
        int m = elem >> 6;
        int k0 = elem & 63;
        int g = k0 >> 3, e0 = k0 & 7;
        float cv[4] = {c4.x, c4.y, c4.z, c4.w};
        short4v hv, lv;
        #pragma unroll
        for (int j = 0; j < 4; ++j) {
            float v = -2.0f * cv[j];
            unsigned short h = f2bf(v);
            hv[j] = (short)h;
            lv[j] = (short)f2bf(v - bf2f(h));
        }
        int dst = (g * 256 + m) * 8 + e0;
        *(short4v*)&chi[dst] = hv;
        *(short4v*)&clo[dst] = lv;
    }
    if (tid < K) s_csq[tid] = csq_g[tid];
    for (int i = tid; i < 256 * SPAD; i += BLOCK) s_sums[i] = 0.0f;
    if (tid < K) s_cnt[tid] = 0.0f;
    __syncthreads();

    const int wv = tid >> 6;          // 0..15
    const int lane = tid & 63;
    const int c15 = lane & 15;        // point-in-group / cent-row-in-tile
    const int g4 = lane >> 4;         // k-chunk group / cent quadrant

    const int base = blockIdx.x * ppb;
    int lim = base + ppb;
    if (lim > N) lim = N;
    const int ngroups = (lim > base) ? ((lim - base + 15) >> 4) : 0;

    #pragma unroll 1
    for (int g0 = wv; g0 < ngroups; g0 += 16) {
        int prow = base + g0 * 16 + c15;
        const bool vA = prow < lim;
        const float* xr = x + (size_t)(vA ? prow : (lim - 1)) * D;

        // ---- this lane's 16 dims of its point + hi/lo bf16 fragments ----
        float xf[16];
        bf16x8 bh[2], bl[2];
        #pragma unroll
        for (int s = 0; s < 2; ++s) {
            const float4* pa = (const float4*)(xr + s * 32 + g4 * 8);
            float4 a0 = pa[0], a1 = pa[1];
            xf[s * 8 + 0] = a0.x; xf[s * 8 + 1] = a0.y;
            xf[s * 8 + 2] = a0.z; xf[s * 8 + 3] = a0.w;
            xf[s * 8 + 4] = a1.x; xf[s * 8 + 5] = a1.y;
            xf[s * 8 + 6] = a1.z; xf[s * 8 + 7] = a1.w;
        }
        #pragma unroll
        for (int s = 0; s < 2; ++s) {
            #pragma unroll
            for (int e = 0; e < 8; ++e) {
                float va = xf[s * 8 + e];
                unsigned short ha = f2bf(va);
                bh[s][e] = (short)ha;
                bl[s][e] = (short)f2bf(va - bf2f(ha));
            }
        }

        // ---- 16 cent-tiles of MFMA ----
        f32x4 acc[16];
        #pragma unroll
        for (int t = 0; t < 16; ++t) {
            f32x4 z = {0.f, 0.f, 0.f, 0.f};
            acc[t] = z;
            #pragma unroll
            for (int s = 0; s < 2; ++s) {
                int ai = (((s * 4 + g4) * 256) + t * 16 + c15) * 8;
                bf16x8 ah = *(const bf16x8*)&chi[ai];
                bf16x8 al = *(const bf16x8*)&clo[ai];
                acc[t] = __builtin_amdgcn_mfma_f32_16x16x32_bf16(ah, bh[s], acc[t], 0, 0, 0);
                acc[t] = __builtin_amdgcn_mfma_f32_16x16x32_bf16(ah, bl[s], acc[t], 0, 0, 0);
                acc[t] = __builtin_amdgcn_mfma_f32_16x16x32_bf16(al, bh[s], acc[t], 0, 0, 0);
            }
        }

        // ---- argmin (+refine), then owner-lane accumulate to LDS ----
        int bk = resolve_bk(acc, s_csq, cent, xr, g4);
        if (vA) {
            #pragma unroll
            for (int s = 0; s < 2; ++s) {
                #pragma unroll
                for (int e = 0; e < 8; ++e)
                    atomicAdd(&s_sums[bk * SPAD + s * 32 + g4 * 8 + e],
                              xf[s * 8 + e]);
            }
            if (g4 == 0) atomicAdd(&s_cnt[bk], 1.0f);
        }
    }

    __syncthreads();
    // ---- flush block partials (unpad) ----
    float* part = parts + (size_t)blockIdx.x * PART_STRIDE;
    for (int i = tid; i < K * D; i += BLOCK) {
        int k = i >> 6, d = i & 63;
        part[i] = s_sums[k * SPAD + d];
    }
    if (tid < K) part[K * D + tid] = s_cnt[tid];
}

// ---------------------------------------------------------------------------
// fused reduce + finalize: one cent per block, 256 threads (4 slices x 64 dims)
__global__ void finalize2(float* __restrict__ cent,
                          const float* __restrict__ parts,
                          float* __restrict__ csq_g,
                          int nb) {
    __shared__ float tmp[4][64];
    __shared__ float tcnt[4];
    int k = blockIdx.x;
    int sl = threadIdx.x >> 6;
    int d = threadIdx.x & 63;
    float s = 0.0f, c = 0.0f;
    for (int b = sl; b < nb; b += 4) {
        const float* pb = parts + (size_t)b * PART_STRIDE;
        s += pb[k * D + d];
        c += pb[K * D + k];
    }
    tmp[sl][d] = s;
    if (d == 0) tcnt[sl] = c;
    __syncthreads();
    if (sl == 0) {
        float st = tmp[0][d] + tmp[1][d] + tmp[2][d] + tmp[3][d];
        float ct = tcnt[0] + tcnt[1] + tcnt[2] + tcnt[3];
        float oldc = cent[k * D + d];
        float nc = (ct > 0.0f) ? (st / ct) : oldc;
        cent[k * D + d] = nc;
        float v = nc * nc;
        #pragma unroll
        for (int off = 32; off > 0; off >>= 1) v += __shfl_down(v, off);
        if (d == 0) csq_g[k] = v;
    }
}

// ---------------------------------------------------------------------------
extern "C" void kernel_launch(void* const* d_in, const int* in_sizes, int n_in,
                              void* d_out, int out_size, void* d_ws, size_t ws_size,
                              hipStream_t stream) {
    const float* x = (const float*)d_in[0];
    const int* init_idx = (const int*)d_in[1];

    int N = in_sizes[0] / D;

    float* cent = (float*)d_out;

    // ws layout: parts[nb][PART_STRIDE] | csq[K]
    int nb = NB_MAX;
    size_t need = ((size_t)NB_MAX * PART_STRIDE + K) * sizeof(float);
    if (ws_size < need) {
        size_t avail = (ws_size > (size_t)K * sizeof(float))
                           ? ws_size - (size_t)K * sizeof(float) : 0;
        nb = (int)(avail / (PART_STRIDE * sizeof(float)));
        if (nb < 1) nb = 1;
    }
    float* parts = (float*)d_ws;
    float* csq = parts + (size_t)nb * PART_STRIDE;

    hipFuncSetAttribute(reinterpret_cast<const void*>(assign_mfma),
                        hipFuncAttributeMaxDynamicSharedMemorySize, SMEM_BYTES);

    init_gather<<<dim3(K), dim3(64), 0, stream>>>(x, init_idx, cent, csq);

    int ppb = (N + nb - 1) / nb;
    for (int it = 0; it < ITERS; ++it) {
        assign_mfma<<<dim3(nb), dim3(BLOCK), SMEM_BYTES, stream>>>(
            x, cent, csq, parts, N, ppb);
        finalize2<<<dim3(K), dim3(256), 0, stream>>>(cent, parts, csq, nb);
    }
}

// Round 20
// 2367.002 us; speedup vs baseline: 8.8009x; 1.0022x over previous
//
#include <hip/hip_runtime.h>

// k-means (Lloyd), N=500000 D=64 K=256 ITERS=10, fp32.
// Round 20: SPAD 66 -> 65 on the r19 best (2372us). Closing the accounting:
// r16's standalone accum kernel cost ~160us/iter (no MFMA!) -> the LDS-atomic
// accumulate (32M ds_add_f32/iter) is ~2/3 of the fused wall. With SPAD=66,
// atomic bank = (2*bk + 8*g4 + e) mod 32: parity locked by e -> each atomic
// instruction uses only 16 of 32 banks (>=4-way conflict guaranteed). SPAD=65
// gives bank = (bk + 8*g4 + e) mod 32 -> all 32 banks, ~2-way expected.
// (DS-atomic serialization apparently isn't in SQ_LDS_BANK_CONFLICT, which is
// why 19 rounds of counter-reading missed it.) Single-variable change.

#define D 64
#define K 256
#define ITERS 10
#define BLOCK 1024
#define NB_MAX 256
#define EPS 2e-3f
#define SPAD 65
#define PART_STRIDE (K * D + K)   // 16640 floats per block partial
// LDS: chi 32KB + clo 32KB + csq 1KB + sums(padded) 65KB + cnt 1KB = 131KB
#define SMEM_BYTES (32768 * 2 + (256 + 256 * SPAD + 256) * 4)

typedef __attribute__((ext_vector_type(8))) short bf16x8;
typedef __attribute__((ext_vector_type(4))) float f32x4;
typedef __attribute__((ext_vector_type(4))) short short4v;

__device__ __forceinline__ unsigned short f2bf(float f) {
    unsigned u = __builtin_bit_cast(unsigned, f);
    u = u + 0x7FFFu + ((u >> 16) & 1u);   // RNE
    return (unsigned short)(u >> 16);
}
__device__ __forceinline__ float bf2f(unsigned short h) {
    unsigned u = ((unsigned)h) << 16;
    return __builtin_bit_cast(float, u);
}

// ---------------------------------------------------------------------------
__global__ void init_gather(const float* __restrict__ x,
                            const int* __restrict__ idx,
                            float* __restrict__ cent,
                            float* __restrict__ csq) {
    int k = blockIdx.x;
    int d = threadIdx.x;
    float v = x[(size_t)idx[k] * D + d];
    cent[k * D + d] = v;
    float s = v * v;
    #pragma unroll
    for (int off = 32; off > 0; off >>= 1) s += __shfl_down(s, off);
    if (d == 0) csq[k] = s;
}

// ---------------------------------------------------------------------------
// score -> argmin (+ exact fp32 refine on near-ties).
__device__ __forceinline__ int resolve_bk(
        const f32x4 (&acc)[16], const float* __restrict__ s_csq,
        const float* __restrict__ cent, const float* __restrict__ xr,
        int g4) {
    // pass 1: global approx min
    float gmin = 3.4e38f;
    int gidx = 0;
    #pragma unroll
    for (int t = 0; t < 16; ++t) {
        f32x4 q = *(const f32x4*)&s_csq[t * 16 + (g4 << 2)];
        #pragma unroll
        for (int r = 0; r < 4; ++r) {
            float sc = acc[t][r] + q[r];
            int m = t * 16 + (g4 << 2) + r;
            if (sc < gmin) { gmin = sc; gidx = m; }
        }
    }
    #pragma unroll
    for (int off = 16; off <= 32; off <<= 1) {
        float so = __shfl_xor(gmin, off);
        int io = __shfl_xor(gidx, off);
        if (so < gmin || (so == gmin && io < gidx)) { gmin = so; gidx = io; }
    }
    // pass 2: candidate mask vs FINAL min
    unsigned long long cmask = 0;
    #pragma unroll
    for (int t = 0; t < 16; ++t) {
        f32x4 q = *(const f32x4*)&s_csq[t * 16 + (g4 << 2)];
        #pragma unroll
        for (int r = 0; r < 4; ++r) {
            float sc = acc[t][r] + q[r];
            if (sc <= gmin + EPS) cmask |= 1ull << (t * 4 + r);
        }
    }
    int nb_ = __popcll(cmask);
    nb_ += __shfl_xor(nb_, 16);
    nb_ += __shfl_xor(nb_, 32);

    int bk = gidx;
    if (__any(nb_ >= 2)) {
        float xsq = 0.0f;
        #pragma unroll
        for (int d = 0; d < D; ++d) xsq += xr[d] * xr[d];
        float eb = 3.4e38f;
        int em = 0x7fffffff;
        unsigned long long mm = cmask;
        while (mm) {
            int b = __ffsll((unsigned long long)mm) - 1;
            mm &= mm - 1;
            int m = ((b >> 2) << 4) + (g4 << 2) + (b & 3);
            const float* cr = cent + m * D;
            float dot = 0.0f;
            #pragma unroll
            for (int d4 = 0; d4 < D; d4 += 4) {
                float4 c4 = *(const float4*)(cr + d4);
                dot += c4.x * xr[d4 + 0];
                dot += c4.y * xr[d4 + 1];
                dot += c4.z * xr[d4 + 2];
                dot += c4.w * xr[d4 + 3];
            }
            float es = xsq - 2.0f * dot + s_csq[m];
            if (es < eb || (es == eb && m < em)) { eb = es; em = m; }
        }
        #pragma unroll
        for (int off = 16; off <= 32; off <<= 1) {
            float so = __shfl_xor(eb, off);
            int io = __shfl_xor(em, off);
            if (so < eb || (so == eb && io < em)) { eb = so; em = io; }
        }
        bk = em;
    }
    return bk;
}

// ---------------------------------------------------------------------------
// fused assign (MFMA + exact refine) + owner-lane LDS accumulate.
// chi/clo LDS layout: [8 k-chunks][256 cents][8 elems] bf16 of (-2*c).
__global__ __launch_bounds__(BLOCK, 4) void assign_mfma(
        const float* __restrict__ x,
        const float* __restrict__ cent,
        const float* __restrict__ csq_g,
        float* __restrict__ parts,
        int N, int ppb) {
    extern __shared__ char smem[];
    short* chi = (short*)smem;                       // 16384 shorts
    short* clo = chi + 16384;                        // 16384 shorts
    float* s_csq = (float*)(clo + 16384);            // 256
    float* s_sums = s_csq + 256;                     // 256*SPAD
    float* s_cnt = s_sums + 256 * SPAD;              // 256

    const int tid = threadIdx.x;

    // ---- stage centroids as -2c hi/lo bf16; zero LDS partials ----
    for (int i = tid; i < (K * D) / 4; i += BLOCK) {
        float4 c4 = ((const float4*)cent)[i];
        int elem = i * 4;
        int m = elem >> 6;
        int k0 = elem & 63;
        int g = k0 >> 3, e0 = k0 & 7;
        float cv[4] = {c4.x, c4.y, c4.z, c4.w};
        short4v hv, lv;
        #pragma unroll
        for (int j = 0; j < 4; ++j) {
            float v = -2.0f * cv[j];
            unsigned short h = f2bf(v);
            hv[j] = (short)h;
            lv[j] = (short)f2bf(v - bf2f(h));
        }
        int dst = (g * 256 + m) * 8 + e0;
        *(short4v*)&chi[dst] = hv;
        *(short4v*)&clo[dst] = lv;
    }
    if (tid < K) s_csq[tid] = csq_g[tid];
    for (int i = tid; i < 256 * SPAD; i += BLOCK) s_sums[i] = 0.0f;
    if (tid < K) s_cnt[tid] = 0.0f;
    __syncthreads();

    const int wv = tid >> 6;          // 0..15
    const int lane = tid & 63;
    const int c15 = lane & 15;        // point-in-group / cent-row-in-tile
    const int g4 = lane >> 4;         // k-chunk group / cent quadrant

    const int base = blockIdx.x * ppb;
    int lim = base + ppb;
    if (lim > N) lim = N;
    const int ngroups = (lim > base) ? ((lim - base + 15) >> 4) : 0;

    #pragma unroll 1
    for (int g0 = wv; g0 < ngroups; g0 += 16) {
        int prow = base + g0 * 16 + c15;
        const bool vA = prow < lim;
        const float* xr = x + (size_t)(vA ? prow : (lim - 1)) * D;

        // ---- this lane's 16 dims of its point + hi/lo bf16 fragments ----
        float xf[16];
        bf16x8 bh[2], bl[2];
        #pragma unroll
        for (int s = 0; s < 2; ++s) {
            const float4* pa = (const float4*)(xr + s * 32 + g4 * 8);
            float4 a0 = pa[0], a1 = pa[1];
            xf[s * 8 + 0] = a0.x; xf[s * 8 + 1] = a0.y;
            xf[s * 8 + 2] = a0.z; xf[s * 8 + 3] = a0.w;
            xf[s * 8 + 4] = a1.x; xf[s * 8 + 5] = a1.y;
            xf[s * 8 + 6] = a1.z; xf[s * 8 + 7] = a1.w;
        }
        #pragma unroll
        for (int s = 0; s < 2; ++s) {
            #pragma unroll
            for (int e = 0; e < 8; ++e) {
                float va = xf[s * 8 + e];
                unsigned short ha = f2bf(va);
                bh[s][e] = (short)ha;
                bl[s][e] = (short)f2bf(va - bf2f(ha));
            }
        }

        // ---- 16 cent-tiles of MFMA ----
        f32x4 acc[16];
        #pragma unroll
        for (int t = 0; t < 16; ++t) {
            f32x4 z = {0.f, 0.f, 0.f, 0.f};
            acc[t] = z;
            #pragma unroll
            for (int s = 0; s < 2; ++s) {
                int ai = (((s * 4 + g4) * 256) + t * 16 + c15) * 8;
                bf16x8 ah = *(const bf16x8*)&chi[ai];
                bf16x8 al = *(const bf16x8*)&clo[ai];
                acc[t] = __builtin_amdgcn_mfma_f32_16x16x32_bf16(ah, bh[s], acc[t], 0, 0, 0);
                acc[t] = __builtin_amdgcn_mfma_f32_16x16x32_bf16(ah, bl[s], acc[t], 0, 0, 0);
                acc[t] = __builtin_amdgcn_mfma_f32_16x16x32_bf16(al, bh[s], acc[t], 0, 0, 0);
            }
        }

        // ---- argmin (+refine), then owner-lane accumulate to LDS ----
        int bk = resolve_bk(acc, s_csq, cent, xr, g4);
        if (vA) {
            #pragma unroll
            for (int s = 0; s < 2; ++s) {
                #pragma unroll
                for (int e = 0; e < 8; ++e)
                    atomicAdd(&s_sums[bk * SPAD + s * 32 + g4 * 8 + e],
                              xf[s * 8 + e]);
            }
            if (g4 == 0) atomicAdd(&s_cnt[bk], 1.0f);
        }
    }

    __syncthreads();
    // ---- flush block partials (unpad) ----
    float* part = parts + (size_t)blockIdx.x * PART_STRIDE;
    for (int i = tid; i < K * D; i += BLOCK) {
        int k = i >> 6, d = i & 63;
        part[i] = s_sums[k * SPAD + d];
    }
    if (tid < K) part[K * D + tid] = s_cnt[tid];
}

// ---------------------------------------------------------------------------
// fused reduce + finalize: one cent per block, 256 threads (4 slices x 64 dims)
__global__ void finalize2(float* __restrict__ cent,
                          const float* __restrict__ parts,
                          float* __restrict__ csq_g,
                          int nb) {
    __shared__ float tmp[4][64];
    __shared__ float tcnt[4];
    int k = blockIdx.x;
    int sl = threadIdx.x >> 6;
    int d = threadIdx.x & 63;
    float s = 0.0f, c = 0.0f;
    for (int b = sl; b < nb; b += 4) {
        const float* pb = parts + (size_t)b * PART_STRIDE;
        s += pb[k * D + d];
        c += pb[K * D + k];
    }
    tmp[sl][d] = s;
    if (d == 0) tcnt[sl] = c;
    __syncthreads();
    if (sl == 0) {
        float st = tmp[0][d] + tmp[1][d] + tmp[2][d] + tmp[3][d];
        float ct = tcnt[0] + tcnt[1] + tcnt[2] + tcnt[3];
        float oldc = cent[k * D + d];
        float nc = (ct > 0.0f) ? (st / ct) : oldc;
        cent[k * D + d] = nc;
        float v = nc * nc;
        #pragma unroll
        for (int off = 32; off > 0; off >>= 1) v += __shfl_down(v, off);
        if (d == 0) csq_g[k] = v;
    }
}

// ---------------------------------------------------------------------------
extern "C" void kernel_launch(void* const* d_in, const int* in_sizes, int n_in,
                              void* d_out, int out_size, void* d_ws, size_t ws_size,
                              hipStream_t stream) {
    const float* x = (const float*)d_in[0];
    const int* init_idx = (const int*)d_in[1];

    int N = in_sizes[0] / D;

    float* cent = (float*)d_out;

    // ws layout: parts[nb][PART_STRIDE] | csq[K]
    int nb = NB_MAX;
    size_t need = ((size_t)NB_MAX * PART_STRIDE + K) * sizeof(float);
    if (ws_size < need) {
        size_t avail = (ws_size > (size_t)K * sizeof(float))
                           ? ws_size - (size_t)K * sizeof(float) : 0;
        nb = (int)(avail / (PART_STRIDE * sizeof(float)));
        if (nb < 1) nb = 1;
    }
    float* parts = (float*)d_ws;
    float* csq = parts + (size_t)nb * PART_STRIDE;

    hipFuncSetAttribute(reinterpret_cast<const void*>(assign_mfma),
                        hipFuncAttributeMaxDynamicSharedMemorySize, SMEM_BYTES);

    init_gather<<<dim3(K), dim3(64), 0, stream>>>(x, init_idx, cent, csq);

    int ppb = (N + nb - 1) / nb;
    for (int it = 0; it < ITERS; ++it) {
        assign_mfma<<<dim3(nb), dim3(BLOCK), SMEM_BYTES, stream>>>(
            x, cent, csq, parts, N, ppb);
        finalize2<<<dim3(K), dim3(256), 0, stream>>>(cent, parts, csq, nb);
    }
}